// Round 11
// baseline (146.405 us; speedup 1.0000x reference)
//
#include <hip/hip_runtime.h>

// Structure (R11): zero 1MiB bitmap -> index-partitioned mark -> probe.
//  zero_kernel: exact-cover uint4 fill of the 262,144-word bitmap (~2us);
//    replaces the former 24MB boundary-scan kernel entirely.
//  mark_kernel: block b owns a2s/sig entries [b*2048,(b+1)*2048). Since a2s
//    is sorted, the block's site span is [first entry, last entry]; bitmap
//    words strictly inside that span are touched by this block ONLY ->
//    accumulate in an LDS window, plain-store interior words, atomicOr the
//    two shared edge words (~2 atomics/block). Out-of-window strays (only
//    possible on adversarial distributions) fall back to global atomicOr.
//  probe_kernel: 8 elems/thread; ss sorted => a wave's bitmap probes land on
//    1-2 cachelines (near-broadcast); NT streaming loads/stores.

typedef int   v4i __attribute__((ext_vector_type(4)));
typedef float v4f __attribute__((ext_vector_type(4)));

static constexpr int BITMAP_WORDS = (2048 * 4096) / 32;  // 262,144 (1 MiB)
static constexpr int BLOCK        = 256;
static constexpr int EPT          = 8;                   // entries per thread
static constexpr int TILE         = BLOCK * EPT;         // 2048 entries/block
static constexpr int WINDOW       = 4096;                // LDS words (16 KB)

// ---- zero the bitmap (exact cover: 256 blocks x 256 threads x 16 B = 1 MiB)
__global__ __launch_bounds__(BLOCK) void zero_kernel(uint4* __restrict__ bm) {
    bm[blockIdx.x * BLOCK + threadIdx.x] = make_uint4(0u, 0u, 0u, 0u);
}

// ---- index-partitioned mark ------------------------------------------------
__global__ __launch_bounds__(BLOCK) void mark_kernel(
    const int* __restrict__ sig, const int* __restrict__ a2s,
    unsigned int* __restrict__ bm, int n)
{
    __shared__ unsigned int win[WINDOW];
    __shared__ int s_lo, s_hi;

    const int blockStart = blockIdx.x * TILE;
    const int e_end      = min(blockStart + TILE, n);
    const int base       = blockStart + threadIdx.x * EPT;
    const int cnt        = max(0, min(EPT, e_end - base));

    int av[EPT], gv[EPT];
    if (cnt == EPT) {
        v4i a0 = __builtin_nontemporal_load((const v4i*)(a2s + base));
        v4i a1 = __builtin_nontemporal_load((const v4i*)(a2s + base + 4));
        v4i g0 = __builtin_nontemporal_load((const v4i*)(sig + base));
        v4i g1 = __builtin_nontemporal_load((const v4i*)(sig + base + 4));
        av[0]=a0.x; av[1]=a0.y; av[2]=a0.z; av[3]=a0.w;
        av[4]=a1.x; av[5]=a1.y; av[6]=a1.z; av[7]=a1.w;
        gv[0]=g0.x; gv[1]=g0.y; gv[2]=g0.z; gv[3]=g0.w;
        gv[4]=g1.x; gv[5]=g1.y; gv[6]=g1.z; gv[7]=g1.w;
    } else {
#pragma unroll
        for (int j = 0; j < EPT; ++j) {
            const int i = base + j;
            const bool ok = i < e_end;
            av[j] = ok ? a2s[i] : 0;
            gv[j] = ok ? sig[i] : 0;   // invalid entries never set bits
        }
    }

    // Block site bounds are just the first/last entries (a2s sorted).
    if (base == blockStart)            s_lo = av[0];          // tid 0 always valid
    if (cnt > 0 && base + cnt == e_end) s_hi = av[cnt - 1];   // owner of last entry
    __syncthreads();

    const int winBase  = s_lo >> 5;
    const int winWords = (s_hi >> 5) - winBase + 1;
    const int wlim     = min(winWords, WINDOW);

    for (int w = threadIdx.x; w < wlim; w += BLOCK) win[w] = 0u;
    __syncthreads();

    // Accumulate: register-merge consecutive same-word bits, then LDS atomicOr.
    int curw = -1; unsigned int curm = 0u;
#pragma unroll
    for (int j = 0; j < EPT; ++j) {
        if (gv[j] > 0) {
            const unsigned int site = (unsigned int)av[j];
            const int w = (int)(site >> 5) - winBase;     // >= 0 (sorted)
            const unsigned int m = 1u << (site & 31u);
            if (w < WINDOW) {
                if (w == curw) curm |= m;
                else { if (curw >= 0) atomicOr(&win[curw], curm); curw = w; curm = m; }
            } else {
                atomicOr(bm + (site >> 5), m);            // adversarial fallback
            }
        }
    }
    if (curw >= 0) atomicOr(&win[curw], curm);
    __syncthreads();

    // Writeback: interior words are exclusively this block's -> plain store;
    // the two edge words may be shared with neighbor blocks -> atomicOr.
    for (int w = threadIdx.x; w < wlim; w += BLOCK) {
        const unsigned int v = win[w];
        const int g = winBase + w;
        if (w == 0 || w == winWords - 1) { if (v) atomicOr(bm + g, v); }
        else bm[g] = v;
    }
}

// ---- probe ------------------------------------------------------------------
__global__ __launch_bounds__(BLOCK) void probe_kernel(
    const int* __restrict__ ss, const float* __restrict__ sc,
    const unsigned int* __restrict__ bm,
    float* __restrict__ rem, float* __restrict__ avail, int n8)
{
    const int t = blockIdx.x * BLOCK + threadIdx.x;
    if (t >= n8) return;
    const int base = t * 8;

    v4i s0 = __builtin_nontemporal_load((const v4i*)(ss + base));
    v4i s1 = __builtin_nontemporal_load((const v4i*)(ss + base + 4));
    v4f f0 = __builtin_nontemporal_load((const v4f*)(sc + base));
    v4f f1 = __builtin_nontemporal_load((const v4f*)(sc + base + 4));

    int   sv[8] = {s0.x, s0.y, s0.z, s0.w, s1.x, s1.y, s1.z, s1.w};
    float fv[8] = {f0.x, f0.y, f0.z, f0.w, f1.x, f1.y, f1.z, f1.w};
    float rv[8], av[8];
#pragma unroll
    for (int j = 0; j < 8; ++j) {
        const unsigned int u   = (unsigned int)sv[j];
        const unsigned int bit = (bm[u >> 5] >> (u & 31u)) & 1u;
        rv[j] = bit ? 0.0f : 1.0f;
        av[j] = bit ? 0.0f : fv[j];
    }

    v4f r0 = {rv[0], rv[1], rv[2], rv[3]};
    v4f r1 = {rv[4], rv[5], rv[6], rv[7]};
    v4f a0 = {av[0], av[1], av[2], av[3]};
    v4f a1 = {av[4], av[5], av[6], av[7]};
    __builtin_nontemporal_store(r0, (v4f*)(rem + base));
    __builtin_nontemporal_store(r1, (v4f*)(rem + base + 4));
    __builtin_nontemporal_store(a0, (v4f*)(avail + base));
    __builtin_nontemporal_store(a1, (v4f*)(avail + base + 4));
}

__global__ void probe_tail_kernel(
    const int* __restrict__ ss, const float* __restrict__ sc,
    const unsigned int* __restrict__ bm,
    float* __restrict__ rem, float* __restrict__ avail, int start, int n)
{
    const int i = start + blockIdx.x * blockDim.x + threadIdx.x;
    if (i >= n) return;
    const unsigned int u   = (unsigned int)ss[i];
    const unsigned int bit = (bm[u >> 5] >> (u & 31u)) & 1u;
    rem[i]   = bit ? 0.0f : 1.0f;
    avail[i] = bit ? 0.0f : sc[i];
}

extern "C" void kernel_launch(void* const* d_in, const int* in_sizes, int n_in,
                              void* d_out, int out_size, void* d_ws, size_t ws_size,
                              hipStream_t stream) {
    const int*   ss  = (const int*)d_in[0];
    const int*   sig = (const int*)d_in[1];
    const int*   a2s = (const int*)d_in[2];
    const float* sc  = (const float*)d_in[3];
    const int n_slice = in_sizes[0];
    const int n_clb   = in_sizes[1];

    unsigned int* bm = (unsigned int*)d_ws;   // 1 MiB bitmap

    zero_kernel<<<BITMAP_WORDS / 4 / BLOCK, BLOCK, 0, stream>>>((uint4*)bm);

    mark_kernel<<<(n_clb + TILE - 1) / TILE, BLOCK, 0, stream>>>(sig, a2s, bm, n_clb);

    float* rem   = (float*)d_out;
    float* avail = rem + n_slice;
    const int n8 = n_slice / 8;
    if (n8 > 0)
        probe_kernel<<<(n8 + BLOCK - 1) / BLOCK, BLOCK, 0, stream>>>(
            ss, sc, bm, rem, avail, n8);
    if (n8 * 8 < n_slice)
        probe_tail_kernel<<<1, 64, 0, stream>>>(ss, sc, bm, rem, avail,
                                                n8 * 8, n_slice);
}